// Round 1
// baseline (359.443 us; speedup 1.0000x reference)
//
#include <hip/hip_runtime.h>
#include <stdint.h>

#define D_  64
#define DP1 65
#define M_  512
#define N_  4096

typedef float f32x4 __attribute__((ext_vector_type(4)));
typedef short s16x8 __attribute__((ext_vector_type(8)));

__device__ inline unsigned short f2bf(float f){
  union {float f; unsigned u;} v; v.f=f;
  unsigned r = v.u + 0x7fffu + ((v.u>>16)&1u);
  return (unsigned short)(r>>16);
}
__device__ inline float bf2f(unsigned short h){
  union {unsigned u; float f;} v; v.u = ((unsigned)h)<<16; return v.f;
}

// ---------------- prep kernels ----------------
__global__ void prep1(const float* __restrict__ A, const float* __restrict__ K0,
                      float* symA, float* sumK2, float* params){
  int t = threadIdx.x;
  for (int idx = t; idx < DP1*DP1; idx += 256){
    int e = idx / DP1, d = idx % DP1;
    float s = 0.f;
    for (int r = 0; r < 10; ++r) s += A[r*DP1+e]*A[r*DP1+d];
    symA[idx] = s;
  }
  for (int m = t; m < M_; m += 256){
    float s = 0.f;
    for (int k = 0; k < D_; ++k){ float v = K0[m*DP1+k]; s += v*v; }
    sumK2[m] = s;
  }
  __syncthreads();
  if (t == 0){
    float tr = 0.f;
    for (int d = 0; d < D_; ++d) tr += symA[d*DP1+d];
    params[0] = tr;
  }
}

// K1 -> bf16 row-major + bf16 transposed (LDS tile transpose)
__global__ void prep2(const float* __restrict__ K1, unsigned short* K1bf, unsigned short* K1Tbf){
  __shared__ float tile[64][65];
  int r0 = blockIdx.x*64, c0 = blockIdx.y*64;
  int t = threadIdx.x;
  for (int it = 0; it < 16; ++it){
    int lin = it*256 + t;
    int r = lin >> 6, c = lin & 63;
    float v = K1[(r0+r)*M_ + c0+c];
    tile[r][c] = v;
    K1bf[(r0+r)*M_ + c0+c] = f2bf(v);
  }
  __syncthreads();
  for (int it = 0; it < 16; ++it){
    int lin = it*256 + t;
    int r = lin >> 6, c = lin & 63;
    K1Tbf[(c0+r)*M_ + (r0+c)] = f2bf(tile[c][r]);
  }
}

// K0T bf16, 80 rows x 512 (rows 65..79 zero). Rows 0..63 double as Kopen^T.
__global__ void prep3(const float* __restrict__ K0, unsigned short* K0Tbf){
  int idx = blockIdx.x*256 + threadIdx.x;
  if (idx >= 80*M_) return;
  int d = idx / M_, i = idx % M_;
  float v = (d < DP1) ? K0[i*DP1 + d] : 0.f;
  K0Tbf[idx] = f2bf(v);
}

// ---------------- opening + elementwise ----------------
__global__ void openk(const float* __restrict__ x, const float* __restrict__ tptr,
                      const float* __restrict__ K0, const float* __restrict__ b0,
                      unsigned short* u0bf, unsigned short* abf,
                      float* trH0, const float* __restrict__ params){
  __shared__ float sS[64][66];
  __shared__ float sK[64][66];
  int n0 = blockIdx.x*64, m0 = blockIdx.y*64;
  int t = threadIdx.x;
  float tval = tptr[0];
  for (int it = 0; it < 17; ++it){
    int lin = it*256 + t;
    if (lin < 64*65){
      int r = lin/65, c = lin%65;
      sS[r][c] = (c < 64) ? x[(n0+r)*64 + c] : tval;
      sK[r][c] = K0[(m0+r)*DP1 + c];
    }
  }
  __syncthreads();
  int tn = (t>>4)*4, tm = (t&15)*4;
  float acc[4][4] = {};
  for (int e = 0; e < DP1; ++e){
    float sv[4], kv[4];
    for (int i=0;i<4;++i){ sv[i]=sS[tn+i][e]; kv[i]=sK[tm+i][e]; }
    for (int i=0;i<4;++i) for(int j=0;j<4;++j) acc[i][j] += sv[i]*kv[j];
  }
  for (int i=0;i<4;++i) for(int j=0;j<4;++j){
    int n = n0+tn+i, m = m0+tm+j;
    float o = acc[i][j] + b0[m];
    float a = tanhf(o);
    float ax = fabsf(o);
    float u0 = ax + log1pf(expf(-2.f*ax));
    u0bf[n*M_+m] = f2bf(u0);
    abf[n*M_+m]  = f2bf(a);
  }
  if (m0 == 0 && t < 64) trH0[n0+t] = params[0];
}

// ---------------- 4096x512x512 GEMMs (MODE 0: lin1, MODE 1: z1) ----------------
template<int MODE>
__launch_bounds__(256, 2)
__global__ void gemm512(const unsigned short* __restrict__ Abf, const unsigned short* __restrict__ Wbf,
                        const float* __restrict__ bias, const float* __restrict__ w,
                        const unsigned short* __restrict__ abf, const float* __restrict__ sumK2,
                        unsigned short* out0, unsigned short* out1, float* trH0){
  int n0 = blockIdx.x*64, i0 = blockIdx.y*64;
  int t = threadIdx.x;
  int wv = t>>6, l = t&63;
  int row = n0 + wv*16 + (l&15);
  int krow = (l>>4)*8;
  f32x4 zero = {0.f,0.f,0.f,0.f};
  f32x4 acc[4]; for (int k=0;k<4;++k) acc[k]=zero;
  for (int j0 = 0; j0 < M_; j0 += 32){
    s16x8 af = *(const s16x8*)(Abf + row*M_ + j0 + krow);
    for (int kt = 0; kt < 4; ++kt){
      s16x8 bf = *(const s16x8*)(Wbf + (i0+kt*16+(l&15))*M_ + j0 + krow);
      acc[kt] = __builtin_amdgcn_mfma_f32_16x16x32_bf16(af, bf, acc[kt], 0, 0, 0);
    }
  }
  if (MODE == 0){
    for (int kt=0;kt<4;++kt) for (int r=0;r<4;++r){
      int n = n0+wv*16+(l>>4)*4+r;
      int i = i0+kt*16+(l&15);
      float v = acc[kt][r] + bias[i];
      float tl = tanhf(v);
      out0[n*M_+i] = f2bf(tl*w[i]);
      out1[n*M_+i] = f2bf((1.f-tl*tl)*w[i]);
    }
  } else {
    for (int r=0;r<4;++r){
      int n = n0+wv*16+(l>>4)*4+r;
      float rowpart = 0.f;
      for (int kt=0;kt<4;++kt){
        int i = i0+kt*16+(l&15);
        float z1 = acc[kt][r] + w[i];
        float a = bf2f(abf[n*M_+i]);
        out0[n*M_+i] = f2bf(a*z1);
        rowpart += (1.f-a*a)*z1*sumK2[i];
      }
      for (int m=1;m<16;m<<=1) rowpart += __shfl_xor(rowpart, m);
      if ((l&15)==0) atomicAdd(&trH0[n], rowpart);
    }
  }
}

// ---------------- z0 = az1 @ K0 (N x 80, K=512) ----------------
__launch_bounds__(256, 2)
__global__ void gemmz0(const unsigned short* __restrict__ az1bf, const unsigned short* __restrict__ K0Tbf,
                       float* z0){
  int n0 = blockIdx.x*64;
  int t = threadIdx.x, wv = t>>6, l = t&63;
  int row = n0 + wv*16 + (l&15);
  int krow = (l>>4)*8;
  f32x4 zero = {0.f,0.f,0.f,0.f};
  f32x4 acc[5]; for (int k=0;k<5;++k) acc[k]=zero;
  for (int j0 = 0; j0 < M_; j0 += 32){
    s16x8 af = *(const s16x8*)(az1bf + row*M_ + j0 + krow);
    for (int dt = 0; dt < 5; ++dt){
      s16x8 bf = *(const s16x8*)(K0Tbf + (dt*16+(l&15))*M_ + j0 + krow);
      acc[dt] = __builtin_amdgcn_mfma_f32_16x16x32_bf16(af, bf, acc[dt], 0, 0, 0);
    }
  }
  for (int dt=0; dt<5; ++dt) for (int r=0;r<4;++r){
    int n = n0+wv*16+(l>>4)*4+r;
    int d = dt*16+(l&15);
    z0[n*80+d] = acc[dt][r];
  }
}

// ---------------- dominant: t1[n] (per-sample 512x64, K=512) ----------------
__launch_bounds__(256, 2)
__global__ void kjk(const unsigned short* __restrict__ K1bf, const unsigned short* __restrict__ K0Tbf,
                    const unsigned short* __restrict__ abf, const unsigned short* __restrict__ cbf,
                    float* t1){
  __shared__ unsigned short Bt[64][520];   // B_n^T: [k][j] = a[j]*Kopen[j][k], padded
  __shared__ float cs[M_];
  __shared__ float redbuf[4];
  int n = blockIdx.x;
  int t = threadIdx.x;
  const unsigned short* arow = abf + n*M_;
  for (int it = 0; it < 16; ++it){
    int cc = it*256 + t;           // 4096 chunks of 8
    int k = cc >> 6;
    int j8 = (cc & 63)*8;
    s16x8 kv = *(const s16x8*)(K0Tbf + k*M_ + j8);
    s16x8 av = *(const s16x8*)(arow + j8);
    s16x8 ov;
    for (int e=0;e<8;++e) ov[e] = (short)f2bf(bf2f((unsigned short)kv[e])*bf2f((unsigned short)av[e]));
    *(s16x8*)(&Bt[k][j8]) = ov;
  }
  for (int i = t; i < M_; i += 256) cs[i] = bf2f(cbf[n*M_+i]);
  __syncthreads();
  int wv = t>>6, l = t&63;
  int krow = (l>>4)*8;
  f32x4 zero = {0.f,0.f,0.f,0.f};
  f32x4 acc[8][4];
  for (int i=0;i<8;++i) for (int k=0;k<4;++k) acc[i][k]=zero;
  for (int j0 = 0; j0 < M_; j0 += 32){
    s16x8 bfr[4];
    for (int kt=0;kt<4;++kt) bfr[kt] = *(const s16x8*)(&Bt[kt*16+(l&15)][j0+krow]);
    for (int it = 0; it < 8; ++it){
      int i0 = (wv*8+it)*16;
      s16x8 af = *(const s16x8*)(K1bf + (i0+(l&15))*M_ + j0 + krow);
      for (int kt=0;kt<4;++kt)
        acc[it][kt] = __builtin_amdgcn_mfma_f32_16x16x32_bf16(af, bfr[kt], acc[it][kt], 0, 0, 0);
    }
  }
  float part = 0.f;
  for (int it=0;it<8;++it){
    int i0 = (wv*8+it)*16;
    for (int r=0;r<4;++r){
      float ci = cs[i0+(l>>4)*4+r];
      float s2 = 0.f;
      for (int kt=0;kt<4;++kt){ float v = acc[it][kt][r]; s2 += v*v; }
      part += ci*s2;
    }
  }
  for (int m=32;m>=1;m>>=1) part += __shfl_xor(part, m);
  if (l == 0) redbuf[wv] = part;
  __syncthreads();
  if (t == 0) t1[n] = redbuf[0]+redbuf[1]+redbuf[2]+redbuf[3];
}

// ---------------- final: grad, outputs ----------------
__global__ void finalk(const float* __restrict__ x, const float* __restrict__ tptr,
                       const float* __restrict__ symA, const float* __restrict__ c_w,
                       const float* __restrict__ z0, const float* __restrict__ trH0,
                       const float* __restrict__ t1, float* out){
  __shared__ float sA[DP1*DP1];
  int t = threadIdx.x;
  for (int i = t; i < DP1*DP1; i += 256) sA[i] = symA[i];
  __syncthreads();
  int wv = t>>6, l = t&63;
  int n = blockIdx.x*4 + wv;
  float tval = tptr[0];
  float sv = x[n*64 + l];
  float acc = z0[n*80 + l] + c_w[l];
  for (int e = 0; e < 64; ++e){
    float se = __shfl(sv, e);
    acc += se * sA[l*DP1 + e];     // symA symmetric
  }
  acc += tval * sA[l*DP1 + 64];
  // grad[64]
  float g64 = sv * sA[64*DP1 + l];
  for (int m=32;m>=1;m>>=1) g64 += __shfl_xor(g64, m);
  g64 += tval*sA[64*DP1+64] + z0[n*80+64] + c_w[64];
  float dz = -acc;
  out[n*64 + l] = dz;
  float q = dz*dz;
  for (int m=32;m>=1;m>>=1) q += __shfl_xor(q, m);
  float costL = 0.5f*q;
  if (l == 0){
    out[N_*64 + n]        = -(trH0[n] + t1[n]);
    out[N_*64 + N_ + n]   = costL;
    out[N_*64 + 2*N_ + n] = fabsf(-g64 + costL);
  }
}

extern "C" void kernel_launch(void* const* d_in, const int* in_sizes, int n_in,
                              void* d_out, int out_size, void* d_ws, size_t ws_size,
                              hipStream_t stream){
  const float* x   = (const float*)d_in[0];
  const float* tp  = (const float*)d_in[1];
  const float* K0  = (const float*)d_in[2];
  const float* b0  = (const float*)d_in[3];
  const float* K1  = (const float*)d_in[4];
  const float* b1  = (const float*)d_in[5];
  const float* w   = (const float*)d_in[6];
  const float* A   = (const float*)d_in[7];
  const float* c_w = (const float*)d_in[8];
  float* out = (float*)d_out;

  char* ws = (char*)d_ws;
  size_t off = 0;
  auto alloc = [&](size_t bytes)->void*{
    void* p = ws + off; off += bytes; off = (off + 255) & ~(size_t)255; return p;
  };
  unsigned short* K1bf   = (unsigned short*)alloc(512*512*2);
  unsigned short* K1Tbf  = (unsigned short*)alloc(512*512*2);
  unsigned short* K0Tbf  = (unsigned short*)alloc(80*512*2);
  float* symA            = (float*)alloc(DP1*DP1*4);
  float* sumK2           = (float*)alloc(512*4);
  float* params          = (float*)alloc(256);
  unsigned short* u0bf   = (unsigned short*)alloc((size_t)N_*M_*2);
  unsigned short* abf    = (unsigned short*)alloc((size_t)N_*M_*2);
  unsigned short* tl1wbf = (unsigned short*)alloc((size_t)N_*M_*2);
  unsigned short* cbf    = (unsigned short*)alloc((size_t)N_*M_*2);
  unsigned short* az1bf  = (unsigned short*)alloc((size_t)N_*M_*2);
  float* z0              = (float*)alloc((size_t)N_*80*4);
  float* trH0            = (float*)alloc(N_*4);
  float* t1              = (float*)alloc(N_*4);

  prep1<<<1, 256, 0, stream>>>(A, K0, symA, sumK2, params);
  prep2<<<dim3(8,8), 256, 0, stream>>>(K1, K1bf, K1Tbf);
  prep3<<<160, 256, 0, stream>>>(K0, K0Tbf);
  openk<<<dim3(N_/64, M_/64), 256, 0, stream>>>(x, tp, K0, b0, u0bf, abf, trH0, params);
  gemm512<0><<<dim3(N_/64, M_/64), 256, 0, stream>>>(u0bf, K1bf, b1, w, nullptr, nullptr,
                                                     tl1wbf, cbf, nullptr);
  gemm512<1><<<dim3(N_/64, M_/64), 256, 0, stream>>>(tl1wbf, K1Tbf, nullptr, w, abf, sumK2,
                                                     az1bf, nullptr, trH0);
  gemmz0<<<N_/64, 256, 0, stream>>>(az1bf, K0Tbf, z0);
  kjk<<<N_, 256, 0, stream>>>(K1bf, K0Tbf, abf, cbf, t1);
  finalk<<<N_/4, 256, 0, stream>>>(x, tp, symA, c_w, z0, trH0, t1, out);
}

// Round 2
// 258.008 us; speedup vs baseline: 1.3931x; 1.3931x over previous
//
#include <hip/hip_runtime.h>
#include <stdint.h>

#define D_  64
#define DP1 65
#define M_  512
#define N_  4096

typedef float f32x4 __attribute__((ext_vector_type(4)));
typedef short s16x8 __attribute__((ext_vector_type(8)));

__device__ inline unsigned short f2bf(float f){
  union {float f; unsigned u;} v; v.f=f;
  unsigned r = v.u + 0x7fffu + ((v.u>>16)&1u);
  return (unsigned short)(r>>16);
}
__device__ inline float bf2f(unsigned short h){
  union {unsigned u; float f;} v; v.u = ((unsigned)h)<<16; return v.f;
}

// ---------------- prep kernels ----------------
__global__ void prep1(const float* __restrict__ A, const float* __restrict__ K0,
                      float* symA, float* sumK2, float* params){
  int t = threadIdx.x;
  for (int idx = t; idx < DP1*DP1; idx += 256){
    int e = idx / DP1, d = idx % DP1;
    float s = 0.f;
    for (int r = 0; r < 10; ++r) s += A[r*DP1+e]*A[r*DP1+d];
    symA[idx] = s;
  }
  for (int m = t; m < M_; m += 256){
    float s = 0.f;
    for (int k = 0; k < D_; ++k){ float v = K0[m*DP1+k]; s += v*v; }
    sumK2[m] = s;
  }
  __syncthreads();
  if (t == 0){
    float tr = 0.f;
    for (int d = 0; d < D_; ++d) tr += symA[d*DP1+d];
    params[0] = tr;
  }
}

// K1 -> bf16 row-major + bf16 transposed (LDS tile transpose)
__global__ void prep2(const float* __restrict__ K1, unsigned short* K1bf, unsigned short* K1Tbf){
  __shared__ float tile[64][65];
  int r0 = blockIdx.x*64, c0 = blockIdx.y*64;
  int t = threadIdx.x;
  for (int it = 0; it < 16; ++it){
    int lin = it*256 + t;
    int r = lin >> 6, c = lin & 63;
    float v = K1[(r0+r)*M_ + c0+c];
    tile[r][c] = v;
    K1bf[(r0+r)*M_ + c0+c] = f2bf(v);
  }
  __syncthreads();
  for (int it = 0; it < 16; ++it){
    int lin = it*256 + t;
    int r = lin >> 6, c = lin & 63;
    K1Tbf[(c0+r)*M_ + (r0+c)] = f2bf(tile[c][r]);
  }
}

// K0T bf16, 80 rows x 512 (rows 65..79 zero). Rows 0..63 double as Kopen^T.
__global__ void prep3(const float* __restrict__ K0, unsigned short* K0Tbf){
  int idx = blockIdx.x*256 + threadIdx.x;
  if (idx >= 80*M_) return;
  int d = idx / M_, i = idx % M_;
  float v = (d < DP1) ? K0[i*DP1 + d] : 0.f;
  K0Tbf[idx] = f2bf(v);
}

// ---------------- opening + elementwise ----------------
__global__ void openk(const float* __restrict__ x, const float* __restrict__ tptr,
                      const float* __restrict__ K0, const float* __restrict__ b0,
                      unsigned short* u0bf, unsigned short* abf,
                      float* trH0, const float* __restrict__ params){
  __shared__ float sS[64][66];
  __shared__ float sK[64][66];
  int n0 = blockIdx.x*64, m0 = blockIdx.y*64;
  int t = threadIdx.x;
  float tval = tptr[0];
  for (int it = 0; it < 17; ++it){
    int lin = it*256 + t;
    if (lin < 64*65){
      int r = lin/65, c = lin%65;
      sS[r][c] = (c < 64) ? x[(n0+r)*64 + c] : tval;
      sK[r][c] = K0[(m0+r)*DP1 + c];
    }
  }
  __syncthreads();
  int tn = (t>>4)*4, tm = (t&15)*4;
  float acc[4][4] = {};
  for (int e = 0; e < DP1; ++e){
    float sv[4], kv[4];
    for (int i=0;i<4;++i){ sv[i]=sS[tn+i][e]; kv[i]=sK[tm+i][e]; }
    for (int i=0;i<4;++i) for(int j=0;j<4;++j) acc[i][j] += sv[i]*kv[j];
  }
  for (int i=0;i<4;++i) for(int j=0;j<4;++j){
    int n = n0+tn+i, m = m0+tm+j;
    float o = acc[i][j] + b0[m];
    float a = tanhf(o);
    float ax = fabsf(o);
    float u0 = ax + log1pf(expf(-2.f*ax));
    u0bf[n*M_+m] = f2bf(u0);
    abf[n*M_+m]  = f2bf(a);
  }
  if (m0 == 0 && t < 64) trH0[n0+t] = params[0];
}

// ---------------- 4096x512x512 GEMMs (MODE 0: lin1, MODE 1: z1) ----------------
template<int MODE>
__launch_bounds__(256, 2)
__global__ void gemm512(const unsigned short* __restrict__ Abf, const unsigned short* __restrict__ Wbf,
                        const float* __restrict__ bias, const float* __restrict__ w,
                        const unsigned short* __restrict__ abf, const float* __restrict__ sumK2,
                        unsigned short* out0, unsigned short* out1, float* trH0){
  int n0 = blockIdx.x*64, i0 = blockIdx.y*64;
  int t = threadIdx.x;
  int wv = t>>6, l = t&63;
  int row = n0 + wv*16 + (l&15);
  int krow = (l>>4)*8;
  f32x4 zero = {0.f,0.f,0.f,0.f};
  f32x4 acc[4]; for (int k=0;k<4;++k) acc[k]=zero;
  for (int j0 = 0; j0 < M_; j0 += 32){
    s16x8 af = *(const s16x8*)(Abf + row*M_ + j0 + krow);
    for (int kt = 0; kt < 4; ++kt){
      s16x8 bf = *(const s16x8*)(Wbf + (i0+kt*16+(l&15))*M_ + j0 + krow);
      acc[kt] = __builtin_amdgcn_mfma_f32_16x16x32_bf16(af, bf, acc[kt], 0, 0, 0);
    }
  }
  if (MODE == 0){
    for (int kt=0;kt<4;++kt) for (int r=0;r<4;++r){
      int n = n0+wv*16+(l>>4)*4+r;
      int i = i0+kt*16+(l&15);
      float v = acc[kt][r] + bias[i];
      float tl = tanhf(v);
      out0[n*M_+i] = f2bf(tl*w[i]);
      out1[n*M_+i] = f2bf((1.f-tl*tl)*w[i]);
    }
  } else {
    for (int r=0;r<4;++r){
      int n = n0+wv*16+(l>>4)*4+r;
      float rowpart = 0.f;
      for (int kt=0;kt<4;++kt){
        int i = i0+kt*16+(l&15);
        float z1 = acc[kt][r] + w[i];
        float a = bf2f(abf[n*M_+i]);
        out0[n*M_+i] = f2bf(a*z1);
        rowpart += (1.f-a*a)*z1*sumK2[i];
      }
      for (int m=1;m<16;m<<=1) rowpart += __shfl_xor(rowpart, m);
      if ((l&15)==0) atomicAdd(&trH0[n], rowpart);
    }
  }
}

// ---------------- z0 = az1 @ K0 (N x 80, K=512) ----------------
__launch_bounds__(256, 2)
__global__ void gemmz0(const unsigned short* __restrict__ az1bf, const unsigned short* __restrict__ K0Tbf,
                       float* z0){
  int n0 = blockIdx.x*64;
  int t = threadIdx.x, wv = t>>6, l = t&63;
  int row = n0 + wv*16 + (l&15);
  int krow = (l>>4)*8;
  f32x4 zero = {0.f,0.f,0.f,0.f};
  f32x4 acc[5]; for (int k=0;k<5;++k) acc[k]=zero;
  for (int j0 = 0; j0 < M_; j0 += 32){
    s16x8 af = *(const s16x8*)(az1bf + row*M_ + j0 + krow);
    for (int dt = 0; dt < 5; ++dt){
      s16x8 bf = *(const s16x8*)(K0Tbf + (dt*16+(l&15))*M_ + j0 + krow);
      acc[dt] = __builtin_amdgcn_mfma_f32_16x16x32_bf16(af, bf, acc[dt], 0, 0, 0);
    }
  }
  for (int dt=0; dt<5; ++dt) for (int r=0;r<4;++r){
    int n = n0+wv*16+(l>>4)*4+r;
    int d = dt*16+(l&15);
    z0[n*80+d] = acc[dt][r];
  }
}

// ---------------- dominant: t1[n0], t1[n0+1] (two per-sample 512x64 GEMMs, K=512) ----
// 8 waves / 512 threads; each wave owns 64 K1 rows and computes BOTH samples so each
// K1 fragment load feeds 8 MFMAs (was 4), and K1 L2 traffic halves.
__launch_bounds__(512, 2)
__global__ void kjk2(const unsigned short* __restrict__ K1bf, const unsigned short* __restrict__ K0Tbf,
                     const unsigned short* __restrict__ abf, const unsigned short* __restrict__ cbf,
                     float* t1){
  __shared__ unsigned short Bt[2][64][520];   // B_s^T: [k][j] = a[j]*Kopen[j][k]
  __shared__ float redbuf[8][2];
  int n0 = blockIdx.x*2;
  int t = threadIdx.x;
  // stage both samples: 2 x 64 rows x 512 shorts, 8 chunks of 8 per thread per sample
  for (int s = 0; s < 2; ++s){
    const unsigned short* arow = abf + (size_t)(n0+s)*M_;
    for (int it = 0; it < 8; ++it){
      int cc = it*512 + t;           // 0..4095 chunks
      int k = cc >> 6;
      int j8 = (cc & 63)*8;
      s16x8 kv = *(const s16x8*)(K0Tbf + k*M_ + j8);
      s16x8 av = *(const s16x8*)(arow + j8);
      s16x8 ov;
      #pragma unroll
      for (int e=0;e<8;++e)
        ov[e] = (short)f2bf(bf2f((unsigned short)kv[e])*bf2f((unsigned short)av[e]));
      *(s16x8*)(&Bt[s][k][j8]) = ov;
    }
  }
  __syncthreads();
  int wv = t>>6, l = t&63;
  int r15 = l & 15, g = l>>4;
  int krow = g*8;
  f32x4 zero = {0.f,0.f,0.f,0.f};
  f32x4 acc[4][4][2];
  #pragma unroll
  for (int i=0;i<4;++i) for (int k=0;k<4;++k) for (int s=0;s<2;++s) acc[i][k][s]=zero;
  const unsigned short* k1base = K1bf + (size_t)(wv*64 + r15)*M_ + krow;
  for (int j0 = 0; j0 < M_; j0 += 32){
    s16x8 af[4];
    #pragma unroll
    for (int it=0; it<4; ++it)
      af[it] = *(const s16x8*)(k1base + it*16*M_ + j0);
    s16x8 bfr[4][2];
    #pragma unroll
    for (int kt=0;kt<4;++kt)
      #pragma unroll
      for (int s=0;s<2;++s)
        bfr[kt][s] = *(const s16x8*)(&Bt[s][kt*16+r15][j0+krow]);
    #pragma unroll
    for (int it=0;it<4;++it)
      #pragma unroll
      for (int kt=0;kt<4;++kt)
        #pragma unroll
        for (int s=0;s<2;++s)
          acc[it][kt][s] = __builtin_amdgcn_mfma_f32_16x16x32_bf16(af[it], bfr[kt][s], acc[it][kt][s], 0, 0, 0);
  }
  float part0 = 0.f, part1 = 0.f;
  #pragma unroll
  for (int it=0;it<4;++it){
    #pragma unroll
    for (int rr=0;rr<4;++rr){
      int i = wv*64 + it*16 + g*4 + rr;
      float c0 = bf2f(cbf[(size_t)n0*M_+i]);
      float c1 = bf2f(cbf[(size_t)(n0+1)*M_+i]);
      float s0=0.f, s1=0.f;
      #pragma unroll
      for (int kt=0;kt<4;++kt){
        float v0 = acc[it][kt][0][rr]; s0 += v0*v0;
        float v1 = acc[it][kt][1][rr]; s1 += v1*v1;
      }
      part0 += c0*s0; part1 += c1*s1;
    }
  }
  for (int m=32;m>=1;m>>=1){
    part0 += __shfl_xor(part0, m);
    part1 += __shfl_xor(part1, m);
  }
  if (l == 0){ redbuf[wv][0] = part0; redbuf[wv][1] = part1; }
  __syncthreads();
  if (t < 2){
    float s = 0.f;
    for (int w2=0; w2<8; ++w2) s += redbuf[w2][t];
    t1[n0+t] = s;
  }
}

// ---------------- final: grad, outputs ----------------
__global__ void finalk(const float* __restrict__ x, const float* __restrict__ tptr,
                       const float* __restrict__ symA, const float* __restrict__ c_w,
                       const float* __restrict__ z0, const float* __restrict__ trH0,
                       const float* __restrict__ t1, float* out){
  __shared__ float sA[DP1*DP1];
  int t = threadIdx.x;
  for (int i = t; i < DP1*DP1; i += 256) sA[i] = symA[i];
  __syncthreads();
  int wv = t>>6, l = t&63;
  int n = blockIdx.x*4 + wv;
  float tval = tptr[0];
  float sv = x[n*64 + l];
  float acc = z0[n*80 + l] + c_w[l];
  for (int e = 0; e < 64; ++e){
    float se = __shfl(sv, e);
    acc += se * sA[l*DP1 + e];     // symA symmetric
  }
  acc += tval * sA[l*DP1 + 64];
  // grad[64]
  float g64 = sv * sA[64*DP1 + l];
  for (int m=32;m>=1;m>>=1) g64 += __shfl_xor(g64, m);
  g64 += tval*sA[64*DP1+64] + z0[n*80+64] + c_w[64];
  float dz = -acc;
  out[n*64 + l] = dz;
  float q = dz*dz;
  for (int m=32;m>=1;m>>=1) q += __shfl_xor(q, m);
  float costL = 0.5f*q;
  if (l == 0){
    out[N_*64 + n]        = -(trH0[n] + t1[n]);
    out[N_*64 + N_ + n]   = costL;
    out[N_*64 + 2*N_ + n] = fabsf(-g64 + costL);
  }
}

extern "C" void kernel_launch(void* const* d_in, const int* in_sizes, int n_in,
                              void* d_out, int out_size, void* d_ws, size_t ws_size,
                              hipStream_t stream){
  const float* x   = (const float*)d_in[0];
  const float* tp  = (const float*)d_in[1];
  const float* K0  = (const float*)d_in[2];
  const float* b0  = (const float*)d_in[3];
  const float* K1  = (const float*)d_in[4];
  const float* b1  = (const float*)d_in[5];
  const float* w   = (const float*)d_in[6];
  const float* A   = (const float*)d_in[7];
  const float* c_w = (const float*)d_in[8];
  float* out = (float*)d_out;

  char* ws = (char*)d_ws;
  size_t off = 0;
  auto alloc = [&](size_t bytes)->void*{
    void* p = ws + off; off += bytes; off = (off + 255) & ~(size_t)255; return p;
  };
  unsigned short* K1bf   = (unsigned short*)alloc(512*512*2);
  unsigned short* K1Tbf  = (unsigned short*)alloc(512*512*2);
  unsigned short* K0Tbf  = (unsigned short*)alloc(80*512*2);
  float* symA            = (float*)alloc(DP1*DP1*4);
  float* sumK2           = (float*)alloc(512*4);
  float* params          = (float*)alloc(256);
  unsigned short* u0bf   = (unsigned short*)alloc((size_t)N_*M_*2);
  unsigned short* abf    = (unsigned short*)alloc((size_t)N_*M_*2);
  unsigned short* tl1wbf = (unsigned short*)alloc((size_t)N_*M_*2);
  unsigned short* cbf    = (unsigned short*)alloc((size_t)N_*M_*2);
  unsigned short* az1bf  = (unsigned short*)alloc((size_t)N_*M_*2);
  float* z0              = (float*)alloc((size_t)N_*80*4);
  float* trH0            = (float*)alloc(N_*4);
  float* t1              = (float*)alloc(N_*4);

  prep1<<<1, 256, 0, stream>>>(A, K0, symA, sumK2, params);
  prep2<<<dim3(8,8), 256, 0, stream>>>(K1, K1bf, K1Tbf);
  prep3<<<160, 256, 0, stream>>>(K0, K0Tbf);
  openk<<<dim3(N_/64, M_/64), 256, 0, stream>>>(x, tp, K0, b0, u0bf, abf, trH0, params);
  gemm512<0><<<dim3(N_/64, M_/64), 256, 0, stream>>>(u0bf, K1bf, b1, w, nullptr, nullptr,
                                                     tl1wbf, cbf, nullptr);
  gemm512<1><<<dim3(N_/64, M_/64), 256, 0, stream>>>(tl1wbf, K1Tbf, nullptr, w, abf, sumK2,
                                                     az1bf, nullptr, trH0);
  gemmz0<<<N_/64, 256, 0, stream>>>(az1bf, K0Tbf, z0);
  kjk2<<<N_/2, 512, 0, stream>>>(K1bf, K0Tbf, abf, cbf, t1);
  finalk<<<N_/4, 256, 0, stream>>>(x, tp, symA, c_w, z0, trH0, t1, out);
}

// Round 3
// 251.688 us; speedup vs baseline: 1.4281x; 1.0251x over previous
//
#include <hip/hip_runtime.h>
#include <stdint.h>

#define D_  64
#define DP1 65
#define M_  512
#define N_  4096

typedef float f32x4 __attribute__((ext_vector_type(4)));
typedef _Float16 h8 __attribute__((ext_vector_type(8)));

// ---------------- prep kernels ----------------
__global__ void prep1(const float* __restrict__ A, const float* __restrict__ K0,
                      float* symA, float* sumK2, float* params){
  int t = threadIdx.x;
  for (int idx = t; idx < DP1*DP1; idx += 256){
    int e = idx / DP1, d = idx % DP1;
    float s = 0.f;
    for (int r = 0; r < 10; ++r) s += A[r*DP1+e]*A[r*DP1+d];
    symA[idx] = s;
  }
  for (int m = t; m < M_; m += 256){
    float s = 0.f;
    for (int k = 0; k < D_; ++k){ float v = K0[m*DP1+k]; s += v*v; }
    sumK2[m] = s;
  }
  __syncthreads();
  if (t == 0){
    float tr = 0.f;
    for (int d = 0; d < D_; ++d) tr += symA[d*DP1+d];
    params[0] = tr;
  }
}

// K1 -> f16 row-major + f16 transposed (LDS tile transpose)
__global__ void prep2(const float* __restrict__ K1, _Float16* K1h, _Float16* K1Th){
  __shared__ float tile[64][65];
  int r0 = blockIdx.x*64, c0 = blockIdx.y*64;
  int t = threadIdx.x;
  for (int it = 0; it < 16; ++it){
    int lin = it*256 + t;
    int r = lin >> 6, c = lin & 63;
    float v = K1[(r0+r)*M_ + c0+c];
    tile[r][c] = v;
    K1h[(r0+r)*M_ + c0+c] = (_Float16)v;
  }
  __syncthreads();
  for (int it = 0; it < 16; ++it){
    int lin = it*256 + t;
    int r = lin >> 6, c = lin & 63;
    K1Th[(c0+r)*M_ + (r0+c)] = (_Float16)tile[c][r];
  }
}

// K0T f16, 80 rows x 512 (rows 65..79 zero). Rows 0..63 double as Kopen^T.
__global__ void prep3(const float* __restrict__ K0, _Float16* K0Th){
  int idx = blockIdx.x*256 + threadIdx.x;
  if (idx >= 80*M_) return;
  int d = idx / M_, i = idx % M_;
  float v = (d < DP1) ? K0[i*DP1 + d] : 0.f;
  K0Th[idx] = (_Float16)v;
}

// ---------------- opening + elementwise ----------------
__global__ void openk(const float* __restrict__ x, const float* __restrict__ tptr,
                      const float* __restrict__ K0, const float* __restrict__ b0,
                      _Float16* u0h, _Float16* ah,
                      float* trH0, const float* __restrict__ params){
  __shared__ float sS[64][66];
  __shared__ float sK[64][66];
  int n0 = blockIdx.x*64, m0 = blockIdx.y*64;
  int t = threadIdx.x;
  float tval = tptr[0];
  for (int it = 0; it < 17; ++it){
    int lin = it*256 + t;
    if (lin < 64*65){
      int r = lin/65, c = lin%65;
      sS[r][c] = (c < 64) ? x[(n0+r)*64 + c] : tval;
      sK[r][c] = K0[(m0+r)*DP1 + c];
    }
  }
  __syncthreads();
  int tn = (t>>4)*4, tm = (t&15)*4;
  float acc[4][4] = {};
  for (int e = 0; e < DP1; ++e){
    float sv[4], kv[4];
    for (int i=0;i<4;++i){ sv[i]=sS[tn+i][e]; kv[i]=sK[tm+i][e]; }
    for (int i=0;i<4;++i) for(int j=0;j<4;++j) acc[i][j] += sv[i]*kv[j];
  }
  for (int i=0;i<4;++i) for(int j=0;j<4;++j){
    int n = n0+tn+i, m = m0+tm+j;
    float o = acc[i][j] + b0[m];
    float a = tanhf(o);
    float ax = fabsf(o);
    float u0 = ax + log1pf(expf(-2.f*ax));
    u0h[n*M_+m] = (_Float16)u0;
    ah[n*M_+m]  = (_Float16)a;
  }
  if (m0 == 0 && t < 64) trH0[n0+t] = params[0];
}

// ---------------- 4096x512x512 GEMMs (MODE 0: lin1, MODE 1: z1) ----------------
template<int MODE>
__launch_bounds__(256, 2)
__global__ void gemm512(const _Float16* __restrict__ Ah, const _Float16* __restrict__ Wh,
                        const float* __restrict__ bias, const float* __restrict__ w,
                        const _Float16* __restrict__ ah, const float* __restrict__ sumK2,
                        _Float16* out0, _Float16* out1, float* trH0){
  int n0 = blockIdx.x*64, i0 = blockIdx.y*64;
  int t = threadIdx.x;
  int wv = t>>6, l = t&63;
  int row = n0 + wv*16 + (l&15);
  int krow = (l>>4)*8;
  f32x4 zero = {0.f,0.f,0.f,0.f};
  f32x4 acc[4]; for (int k=0;k<4;++k) acc[k]=zero;
  for (int j0 = 0; j0 < M_; j0 += 32){
    h8 af = *(const h8*)(Ah + row*M_ + j0 + krow);
    for (int kt = 0; kt < 4; ++kt){
      h8 bf = *(const h8*)(Wh + (i0+kt*16+(l&15))*M_ + j0 + krow);
      acc[kt] = __builtin_amdgcn_mfma_f32_16x16x32_f16(af, bf, acc[kt], 0, 0, 0);
    }
  }
  if (MODE == 0){
    for (int kt=0;kt<4;++kt) for (int r=0;r<4;++r){
      int n = n0+wv*16+(l>>4)*4+r;
      int i = i0+kt*16+(l&15);
      float v = acc[kt][r] + bias[i];
      float tl = tanhf(v);
      out0[n*M_+i] = (_Float16)(tl*w[i]);
      out1[n*M_+i] = (_Float16)((1.f-tl*tl)*w[i]);
    }
  } else {
    for (int r=0;r<4;++r){
      int n = n0+wv*16+(l>>4)*4+r;
      float rowpart = 0.f;
      for (int kt=0;kt<4;++kt){
        int i = i0+kt*16+(l&15);
        float z1 = acc[kt][r] + w[i];
        float a = (float)ah[n*M_+i];
        out0[n*M_+i] = (_Float16)(a*z1);
        rowpart += (1.f-a*a)*z1*sumK2[i];
      }
      for (int m=1;m<16;m<<=1) rowpart += __shfl_xor(rowpart, m);
      if ((l&15)==0) atomicAdd(&trH0[n], rowpart);
    }
  }
}

// ---------------- z0 = az1 @ K0 (N x 80, K=512) ----------------
__launch_bounds__(256, 2)
__global__ void gemmz0(const _Float16* __restrict__ az1h, const _Float16* __restrict__ K0Th,
                       float* z0){
  int n0 = blockIdx.x*64;
  int t = threadIdx.x, wv = t>>6, l = t&63;
  int row = n0 + wv*16 + (l&15);
  int krow = (l>>4)*8;
  f32x4 zero = {0.f,0.f,0.f,0.f};
  f32x4 acc[5]; for (int k=0;k<5;++k) acc[k]=zero;
  for (int j0 = 0; j0 < M_; j0 += 32){
    h8 af = *(const h8*)(az1h + row*M_ + j0 + krow);
    for (int dt = 0; dt < 5; ++dt){
      h8 bf = *(const h8*)(K0Th + (dt*16+(l&15))*M_ + j0 + krow);
      acc[dt] = __builtin_amdgcn_mfma_f32_16x16x32_f16(af, bf, acc[dt], 0, 0, 0);
    }
  }
  for (int dt=0; dt<5; ++dt) for (int r=0;r<4;++r){
    int n = n0+wv*16+(l>>4)*4+r;
    int d = dt*16+(l&15);
    z0[n*80+d] = acc[dt][r];
  }
}

// ---------------- dominant: t1[n0], t1[n0+1] (two per-sample 512x64 GEMMs, K=512) ----
// 8 waves / 512 threads; each wave owns 64 K1 rows, computes both samples.
// Bt is XOR-swizzled in 16B chunks (chunk ^= row&7) -> conflict-free ds_read_b128,
// stride 512 (no pad). Staging uses packed fp16 multiply. af is prefetched 1 j0-step
// ahead so K1 L2 latency hides under the 32-MFMA block.
__launch_bounds__(512, 2)
__global__ void kjk2(const _Float16* __restrict__ K1h, const _Float16* __restrict__ K0Th,
                     const _Float16* __restrict__ ah, const _Float16* __restrict__ ch,
                     float* t1){
  __shared__ _Float16 Bt[2][64*512];
  __shared__ float redbuf[8][2];
  int n0 = blockIdx.x*2;
  int t = threadIdx.x;
  for (int s = 0; s < 2; ++s){
    const _Float16* arow = ah + (size_t)(n0+s)*M_;
    #pragma unroll
    for (int it = 0; it < 8; ++it){
      int cc = it*512 + t;          // 0..4095: (row k)x(16B chunk c)
      int k = cc >> 6;
      int c = cc & 63;
      h8 kv = *(const h8*)(K0Th + k*M_ + c*8);
      h8 av = *(const h8*)(arow + c*8);
      h8 ov = kv * av;              // v_pk_mul_f16 x4
      *(h8*)(&Bt[s][k*512 + ((c ^ (k & 7))*8)]) = ov;
    }
  }
  __syncthreads();
  int wv = t>>6, l = t&63;
  int r15 = l & 15, g = l>>4;
  f32x4 zero = {0.f,0.f,0.f,0.f};
  f32x4 acc[4][4][2];
  #pragma unroll
  for (int i=0;i<4;++i) for (int k=0;k<4;++k) for (int s=0;s<2;++s) acc[i][k][s]=zero;
  const _Float16* k1base = K1h + (size_t)(wv*64 + r15)*M_ + g*8;
  h8 af[4], afn[4];
  #pragma unroll
  for (int it=0; it<4; ++it) af[it] = *(const h8*)(k1base + it*16*M_);
  for (int j0 = 0; j0 < M_; j0 += 32){
    if (j0 + 32 < M_){
      #pragma unroll
      for (int it=0; it<4; ++it)
        afn[it] = *(const h8*)(k1base + it*16*M_ + j0 + 32);
    }
    h8 bfr[4][2];
    #pragma unroll
    for (int kt=0;kt<4;++kt){
      int row = kt*16 + r15;
      int c = ((j0>>3) + g) ^ (row & 7);
      #pragma unroll
      for (int s=0;s<2;++s)
        bfr[kt][s] = *(const h8*)(&Bt[s][row*512 + c*8]);
    }
    #pragma unroll
    for (int it=0;it<4;++it)
      #pragma unroll
      for (int kt=0;kt<4;++kt)
        #pragma unroll
        for (int s=0;s<2;++s)
          acc[it][kt][s] = __builtin_amdgcn_mfma_f32_16x16x32_f16(af[it], bfr[kt][s], acc[it][kt][s], 0, 0, 0);
    #pragma unroll
    for (int it=0;it<4;++it) af[it] = afn[it];
  }
  float part0 = 0.f, part1 = 0.f;
  #pragma unroll
  for (int it=0;it<4;++it){
    #pragma unroll
    for (int rr=0;rr<4;++rr){
      int i = wv*64 + it*16 + g*4 + rr;
      float c0 = (float)ch[(size_t)n0*M_+i];
      float c1 = (float)ch[(size_t)(n0+1)*M_+i];
      float s0=0.f, s1=0.f;
      #pragma unroll
      for (int kt=0;kt<4;++kt){
        float v0 = acc[it][kt][0][rr]; s0 += v0*v0;
        float v1 = acc[it][kt][1][rr]; s1 += v1*v1;
      }
      part0 += c0*s0; part1 += c1*s1;
    }
  }
  for (int m=32;m>=1;m>>=1){
    part0 += __shfl_xor(part0, m);
    part1 += __shfl_xor(part1, m);
  }
  if (l == 0){ redbuf[wv][0] = part0; redbuf[wv][1] = part1; }
  __syncthreads();
  if (t < 2){
    float s = 0.f;
    for (int w2=0; w2<8; ++w2) s += redbuf[w2][t];
    t1[n0+t] = s;
  }
}

// ---------------- final: grad, outputs ----------------
__global__ void finalk(const float* __restrict__ x, const float* __restrict__ tptr,
                       const float* __restrict__ symA, const float* __restrict__ c_w,
                       const float* __restrict__ z0, const float* __restrict__ trH0,
                       const float* __restrict__ t1, float* out){
  __shared__ float sA[DP1*DP1];
  int t = threadIdx.x;
  for (int i = t; i < DP1*DP1; i += 256) sA[i] = symA[i];
  __syncthreads();
  int wv = t>>6, l = t&63;
  int n = blockIdx.x*4 + wv;
  float tval = tptr[0];
  float sv = x[n*64 + l];
  float acc = z0[n*80 + l] + c_w[l];
  for (int e = 0; e < 64; ++e){
    float se = __shfl(sv, e);
    acc += se * sA[l*DP1 + e];     // symA symmetric
  }
  acc += tval * sA[l*DP1 + 64];
  // grad[64]
  float g64 = sv * sA[64*DP1 + l];
  for (int m=32;m>=1;m>>=1) g64 += __shfl_xor(g64, m);
  g64 += tval*sA[64*DP1+64] + z0[n*80+64] + c_w[64];
  float dz = -acc;
  out[n*64 + l] = dz;
  float q = dz*dz;
  for (int m=32;m>=1;m>>=1) q += __shfl_xor(q, m);
  float costL = 0.5f*q;
  if (l == 0){
    out[N_*64 + n]        = -(trH0[n] + t1[n]);
    out[N_*64 + N_ + n]   = costL;
    out[N_*64 + 2*N_ + n] = fabsf(-g64 + costL);
  }
}

extern "C" void kernel_launch(void* const* d_in, const int* in_sizes, int n_in,
                              void* d_out, int out_size, void* d_ws, size_t ws_size,
                              hipStream_t stream){
  const float* x   = (const float*)d_in[0];
  const float* tp  = (const float*)d_in[1];
  const float* K0  = (const float*)d_in[2];
  const float* b0  = (const float*)d_in[3];
  const float* K1  = (const float*)d_in[4];
  const float* b1  = (const float*)d_in[5];
  const float* w   = (const float*)d_in[6];
  const float* A   = (const float*)d_in[7];
  const float* c_w = (const float*)d_in[8];
  float* out = (float*)d_out;

  char* ws = (char*)d_ws;
  size_t off = 0;
  auto alloc = [&](size_t bytes)->void*{
    void* p = ws + off; off += bytes; off = (off + 255) & ~(size_t)255; return p;
  };
  _Float16* K1h   = (_Float16*)alloc(512*512*2);
  _Float16* K1Th  = (_Float16*)alloc(512*512*2);
  _Float16* K0Th  = (_Float16*)alloc(80*512*2);
  float* symA     = (float*)alloc(DP1*DP1*4);
  float* sumK2    = (float*)alloc(512*4);
  float* params   = (float*)alloc(256);
  _Float16* u0h   = (_Float16*)alloc((size_t)N_*M_*2);
  _Float16* ah    = (_Float16*)alloc((size_t)N_*M_*2);
  _Float16* tl1wh = (_Float16*)alloc((size_t)N_*M_*2);
  _Float16* ch    = (_Float16*)alloc((size_t)N_*M_*2);
  _Float16* az1h  = (_Float16*)alloc((size_t)N_*M_*2);
  float* z0       = (float*)alloc((size_t)N_*80*4);
  float* trH0     = (float*)alloc(N_*4);
  float* t1       = (float*)alloc(N_*4);

  prep1<<<1, 256, 0, stream>>>(A, K0, symA, sumK2, params);
  prep2<<<dim3(8,8), 256, 0, stream>>>(K1, K1h, K1Th);
  prep3<<<160, 256, 0, stream>>>(K0, K0Th);
  openk<<<dim3(N_/64, M_/64), 256, 0, stream>>>(x, tp, K0, b0, u0h, ah, trH0, params);
  gemm512<0><<<dim3(N_/64, M_/64), 256, 0, stream>>>(u0h, K1h, b1, w, nullptr, nullptr,
                                                     tl1wh, ch, nullptr);
  gemm512<1><<<dim3(N_/64, M_/64), 256, 0, stream>>>(tl1wh, K1Th, nullptr, w, ah, sumK2,
                                                     az1h, nullptr, trH0);
  gemmz0<<<N_/64, 256, 0, stream>>>(az1h, K0Th, z0);
  kjk2<<<N_/2, 512, 0, stream>>>(K1h, K0Th, ah, ch, t1);
  finalk<<<N_/4, 256, 0, stream>>>(x, tp, symA, c_w, z0, trH0, t1, out);
}